// Round 3
// baseline (1282.497 us; speedup 1.0000x reference)
//
#include <hip/hip_runtime.h>

// MoE top-2/8, D=1024, H=4096, 4096 tokens (8192 pairs).
// bf16x3 split precision via K-expansion: A'=[Ah;Al;Ah], B'=[Bh;Bh;Bl] (K'=3K)
// -> plain bf16 GEMM, global_load_lds staging, 2-phase double-buffered schedule.
// Workspace-tiered: FULL (3-term both GEMMs), MIDH (drop h-lo), MINI (drop W-lo too).

#define NTOK   4096
#define DMODEL 1024
#define HDIM   4096
#define NEXP   8
#define NPAIR  8192

typedef __attribute__((ext_vector_type(8))) short short8;
typedef __attribute__((ext_vector_type(4))) float floatx4;

__device__ __forceinline__ short f2bf(float f) {
  unsigned u = __float_as_uint(f);
  u += 0x7FFFu + ((u >> 16) & 1u);          // RNE
  return (short)(u >> 16);
}
__device__ __forceinline__ float bf2f(short s) {
  return __uint_as_float(((unsigned)(unsigned short)s) << 16);
}

// async global->LDS, 16B per lane. LDS dest must be wave-uniform base + lane*16;
// &lds[t*8] with consecutive lanes is exactly that (linear tile layout).
__device__ __forceinline__ void gll16(const short* g, short* l) {
  __builtin_amdgcn_global_load_lds((const __attribute__((address_space(1))) void*)g,
                                   (__attribute__((address_space(3))) void*)l, 16, 0, 0);
}

// ---------------- gating: 1 wave per token ----------------
__global__ __launch_bounds__(256) void k_gate(
    const float* __restrict__ x, const float* __restrict__ Wg,
    const float* __restrict__ bg, int* __restrict__ counts,
    int* __restrict__ tok_e, float* __restrict__ tok_w) {
  const int token = blockIdx.x * 4 + (threadIdx.x >> 6);
  const int lane = threadIdx.x & 63;
  const float* xr = x + (size_t)token * DMODEL;
  float a[8] = {0.f,0.f,0.f,0.f,0.f,0.f,0.f,0.f};
  for (int d = lane; d < DMODEL; d += 64) {
    const float xv = xr[d];
    const float4 w0 = *reinterpret_cast<const float4*>(Wg + d * 8);
    const float4 w1 = *reinterpret_cast<const float4*>(Wg + d * 8 + 4);
    a[0] += xv * w0.x; a[1] += xv * w0.y; a[2] += xv * w0.z; a[3] += xv * w0.w;
    a[4] += xv * w1.x; a[5] += xv * w1.y; a[6] += xv * w1.z; a[7] += xv * w1.w;
  }
  #pragma unroll
  for (int e = 0; e < 8; ++e)
    #pragma unroll
    for (int off = 32; off; off >>= 1)
      a[e] += __shfl_xor(a[e], off);
  if (lane == 0) {
    float l[8];
    #pragma unroll
    for (int e = 0; e < 8; ++e) l[e] = a[e] + bg[e];
    int e0 = 0;
    #pragma unroll
    for (int e = 1; e < 8; ++e) if (l[e] > l[e0]) e0 = e;
    int e1 = (e0 == 0) ? 1 : 0;
    #pragma unroll
    for (int e = 0; e < 8; ++e) if (e != e0 && l[e] > l[e1]) e1 = e;
    const float p  = expf(l[e1] - l[e0]);   // top-2 renorm softmax == sigmoid of gap
    const float w0 = 1.0f / (1.0f + p);
    const float w1 = p * w0;
    tok_e[token * 2]     = e0;  tok_e[token * 2 + 1] = e1;
    tok_w[token * 2]     = w0;  tok_w[token * 2 + 1] = w1;
    atomicAdd(&counts[e0], 1);  atomicAdd(&counts[e1], 1);
  }
}

// ---------------- scatter pairs grouped by expert ----------------
__global__ __launch_bounds__(256) void k_scatter(
    const int* __restrict__ counts, int* __restrict__ bases,
    const int* __restrict__ tok_e, const float* __restrict__ tok_w,
    int* __restrict__ pair_token, float* __restrict__ pair_w) {
  __shared__ int sbase[8];
  __shared__ int scur[8];
  const int tid = threadIdx.x;
  if (tid < 8) {
    int b = 0;
    for (int i = 0; i < tid; ++i) b += counts[i];
    sbase[tid] = b; bases[tid] = b; scur[tid] = 0;
  }
  __syncthreads();
  for (int i = tid; i < NPAIR; i += 256) {
    const int e = tok_e[i];
    const int slot = sbase[e] + atomicAdd(&scur[e], 1);
    pair_token[slot] = i >> 1;
    pair_w[slot] = tok_w[i];
  }
}

// ---------------- x -> bf16 hi/lo planes ----------------
__global__ __launch_bounds__(256) void k_xcvt(
    const float* __restrict__ x, short* __restrict__ xhi, short* __restrict__ xlo) {
  const int i = (blockIdx.x * 256 + threadIdx.x) * 8;
  const float4 a = *reinterpret_cast<const float4*>(x + i);
  const float4 b = *reinterpret_cast<const float4*>(x + i + 4);
  const float v[8] = {a.x, a.y, a.z, a.w, b.x, b.y, b.z, b.w};
  short8 h, l;
  #pragma unroll
  for (int j = 0; j < 8; ++j) {
    const short hv = f2bf(v[j]);
    h[j] = hv; l[j] = f2bf(v[j] - bf2f(hv));
  }
  *reinterpret_cast<short8*>(xhi + i) = h;
  *reinterpret_cast<short8*>(xlo + i) = l;
}

// ---------------- W [e][K][N] fp32 -> Wt hi/lo [e][N][K] bf16 ----------------
__global__ __launch_bounds__(256) void k_wt(
    const float* __restrict__ W, int K, int N,
    short* __restrict__ Whi, short* __restrict__ Wlo, int wlo) {
  __shared__ float tile[64][65];
  const int tilesN = N >> 6;
  const int per_e = (K >> 6) * tilesN;
  const int bid = blockIdx.x;
  const int e = bid / per_e;
  const int rem = bid - e * per_e;
  const int tk = rem / tilesN;
  const int tn = rem - tk * tilesN;
  const int t = threadIdx.x;
  const int r = t >> 2, c0 = (t & 3) << 4;
  const float* src = W + (size_t)e * K * N + (size_t)(tk * 64 + r) * N + tn * 64 + c0;
  #pragma unroll
  for (int i = 0; i < 4; ++i) {
    const float4 v = *reinterpret_cast<const float4*>(src + i * 4);
    tile[r][c0 + i*4 + 0] = v.x; tile[r][c0 + i*4 + 1] = v.y;
    tile[r][c0 + i*4 + 2] = v.z; tile[r][c0 + i*4 + 3] = v.w;
  }
  __syncthreads();
  const int n = t >> 2, k0 = (t & 3) << 4;
  const size_t ob = (size_t)e * N * K + (size_t)(tn * 64 + n) * K + tk * 64 + k0;
  short8 h0, h1, l0, l1;
  #pragma unroll
  for (int i = 0; i < 8; ++i) {
    float f = tile[k0 + i][n];
    short hv = f2bf(f); h0[i] = hv; l0[i] = f2bf(f - bf2f(hv));
    f = tile[k0 + 8 + i][n];
    hv = f2bf(f); h1[i] = hv; l1[i] = f2bf(f - bf2f(hv));
  }
  *reinterpret_cast<short8*>(&Whi[ob])     = h0;
  *reinterpret_cast<short8*>(&Whi[ob + 8]) = h1;
  if (wlo) {
    *reinterpret_cast<short8*>(&Wlo[ob])     = l0;
    *reinterpret_cast<short8*>(&Wlo[ob + 8]) = l1;
  }
}

// ---------------- grouped GEMM, K-expanded split precision ----------------
// MODE 0: segs {AhBh, AlBh, AhBl}   MODE 1: {AhBh, AhBl}
// MODE 2: segs {AhBh, AlBh}         MODE 3: {AhBh}
// FFN1: A rows gathered via pair_token; epilogue gelu -> h plane(s) (WLO).
// FFN2: A rows = h slots; epilogue atomicAdd(w * (acc + b2)).
template<int KDIM, int NDIM, bool FFN1, int MODE, bool WLO>
__global__ __launch_bounds__(256, 2) void k_gemm(
    const short* __restrict__ Ahi, const short* __restrict__ Alo,
    const short* __restrict__ Bhi, const short* __restrict__ Blo,
    const float* __restrict__ bias,
    const int* __restrict__ counts, const int* __restrict__ bases,
    const int* __restrict__ pair_token, const float* __restrict__ pair_w,
    short* __restrict__ Ohi, short* __restrict__ Olo,
    float* __restrict__ out) {
  constexpr int NSEG  = KDIM / 32;                       // K-steps per segment
  constexpr int TERMS = (MODE == 0) ? 3 : ((MODE == 3) ? 1 : 2);
  constexpr int NKT   = TERMS * NSEG;
  constexpr int NT    = NDIM / 128;
  __shared__ short As[2][4096], Bs[2][4096];   // 2 x [128][32] each, 32 KB total

  const int bid = blockIdx.x;
  const int e   = bid / (16 * NT);
  const int rem = bid - e * (16 * NT);
  const int mt0 = rem / NT;
  const int nt  = rem - mt0 * NT;
  const int n_e  = counts[e];
  const int base = bases[e];

  const int t = threadIdx.x, lane = t & 63, wid = t >> 6;
  const int wr = wid >> 1, wc = wid & 1;
  const int fr = lane & 15, fks = (lane >> 4) << 3;
  const int sr = t >> 2;                // staging row within 64-row half
  const int sc = (t & 3) << 3;          // staging k offset (shorts)

  const size_t brow0 = (size_t)(e * NDIM + nt * 128 + sr) * KDIM + sc;
  const size_t brow1 = brow0 + (size_t)64 * KDIM;

  for (int mt = mt0; mt * 128 < n_e; mt += 16) {
    const int row0 = base + mt * 128;
    int rows_in = n_e - mt * 128; if (rows_in > 128) rows_in = 128;

    int s0 = row0 + sr;      if (s0 > NPAIR - 1) s0 = NPAIR - 1;
    int s1 = row0 + 64 + sr; if (s1 > NPAIR - 1) s1 = NPAIR - 1;
    const size_t arow0 = (size_t)(FFN1 ? pair_token[s0] : s0) * KDIM + sc;
    const size_t arow1 = (size_t)(FFN1 ? pair_token[s1] : s1) * KDIM + sc;

    floatx4 acc[4][4];
    #pragma unroll
    for (int m = 0; m < 4; ++m)
      #pragma unroll
      for (int n = 0; n < 4; ++n) acc[m][n] = floatx4{0.f, 0.f, 0.f, 0.f};

    auto STAGE = [&](int nb, int kt) {
      const int seg  = kt / NSEG;
      const int koff = (kt - seg * NSEG) * 32;
      const short* pA = Ahi;
      const short* pB = Bhi;
      if (MODE == 0) { if (seg == 1) pA = Alo; if (seg == 2) pB = Blo; }
      if (MODE == 1) { if (seg == 1) pB = Blo; }
      if (MODE == 2) { if (seg == 1) pA = Alo; }
      gll16(pA + arow0 + koff, &As[nb][t * 8]);
      gll16(pA + arow1 + koff, &As[nb][2048 + t * 8]);
      gll16(pB + brow0 + koff, &Bs[nb][t * 8]);
      gll16(pB + brow1 + koff, &Bs[nb][2048 + t * 8]);
    };

    STAGE(0, 0);
    __syncthreads();                               // drains vmcnt(0): buf0 ready
    #pragma unroll 1
    for (int kt = 0; kt < NKT; ++kt) {
      const int cb = kt & 1;
      if (kt + 1 < NKT) STAGE(cb ^ 1, kt + 1);     // prefetch overlaps MFMA
      short8 fa[4], fb[4];
      #pragma unroll
      for (int m = 0; m < 4; ++m)
        fa[m] = *reinterpret_cast<const short8*>(&As[cb][(wr * 64 + m * 16 + fr) * 32 + fks]);
      #pragma unroll
      for (int n = 0; n < 4; ++n)
        fb[n] = *reinterpret_cast<const short8*>(&Bs[cb][(wc * 64 + n * 16 + fr) * 32 + fks]);
      #pragma unroll
      for (int m = 0; m < 4; ++m)
        #pragma unroll
        for (int n = 0; n < 4; ++n)
          acc[m][n] = __builtin_amdgcn_mfma_f32_16x16x32_bf16(fa[m], fb[n], acc[m][n], 0, 0, 0);
      __syncthreads();                             // drains vmcnt(0)+lgkmcnt(0)
    }

    const int jr = (lane >> 4) << 2;
    #pragma unroll
    for (int m = 0; m < 4; ++m)
      #pragma unroll
      for (int j = 0; j < 4; ++j) {
        const int rl = wr * 64 + m * 16 + jr + j;
        if (rl < rows_in) {
          const int slot = row0 + rl;
          if (FFN1) {
            const size_t ob = (size_t)slot * NDIM;
            #pragma unroll
            for (int n = 0; n < 4; ++n) {
              const int col = nt * 128 + wc * 64 + n * 16 + fr;
              float v = acc[m][n][j] + bias[e * NDIM + col];
              v = 0.5f * v * (1.0f + erff(v * 0.70710678118654752440f));  // exact gelu
              const short hv = f2bf(v);
              Ohi[ob + col] = hv;
              if (WLO) Olo[ob + col] = f2bf(v - bf2f(hv));
            }
          } else {
            const int token = pair_token[slot];
            const float w = pair_w[slot];
            float* op = out + (size_t)token * NDIM;
            #pragma unroll
            for (int n = 0; n < 4; ++n) {
              const int col = nt * 128 + wc * 64 + n * 16 + fr;
              atomicAdd(&op[col], w * (acc[m][n][j] + bias[e * NDIM + col]));
            }
          }
        }
      }
  }
}

extern "C" void kernel_launch(void* const* d_in, const int* in_sizes, int n_in,
                              void* d_out, int out_size, void* d_ws, size_t ws_size,
                              hipStream_t stream) {
  const float* x  = (const float*)d_in[0];
  const float* Wg = (const float*)d_in[1];
  const float* bg = (const float*)d_in[2];
  const float* W1 = (const float*)d_in[3];
  const float* b1 = (const float*)d_in[4];
  const float* W2 = (const float*)d_in[5];
  const float* b2 = (const float*)d_in[6];
  float* out = (float*)d_out;

  char* ws = (char*)d_ws;
  int*   counts     = (int*)(ws + 0);
  int*   bases      = (int*)(ws + 64);
  int*   tok_e      = (int*)(ws + 256);
  float* tok_w      = (float*)(ws + 256 + 32768);
  int*   pair_token = (int*)(ws + 256 + 65536);
  float* pair_w     = (float*)(ws + 256 + 98304);

  const size_t baseOff = 262144;
  const size_t xN = (size_t)NTOK * DMODEL;        // shorts per x plane
  const size_t wN = (size_t)NEXP * DMODEL * HDIM; // shorts per W plane
  const size_t hN = (size_t)NPAIR * HDIM;         // shorts per h plane
  const size_t needFULL = baseOff + 2 * (2 * xN + 2 * wN + 2 * hN); // 285.5 MB
  const size_t needMIDH = baseOff + 2 * (2 * xN + 2 * wN + hN);     // 218.4 MB
  const int tier = (ws_size >= needFULL) ? 0 : ((ws_size >= needMIDH) ? 1 : 2);

  short* xhi = (short*)(ws + baseOff);
  short* xlo = xhi + xN;
  short* Whi = xlo + xN;
  short* Wlo = (tier <= 1) ? (Whi + wN) : Whi;    // MINI: no W-lo plane
  short* hhi = (tier <= 1) ? (Wlo + wN) : (Whi + wN);
  short* hlo = (tier == 0) ? (hhi + hN) : hhi;    // MIDH/MINI: no h-lo plane

  hipMemsetAsync(counts, 0, 64, stream);
  hipMemsetAsync(d_out, 0, (size_t)out_size * sizeof(float), stream);
  k_gate<<<NTOK / 4, 256, 0, stream>>>(x, Wg, bg, counts, tok_e, tok_w);
  k_scatter<<<1, 256, 0, stream>>>(counts, bases, tok_e, tok_w, pair_token, pair_w);
  k_xcvt<<<(NTOK * DMODEL) / (256 * 8), 256, 0, stream>>>(x, xhi, xlo);

  const int g1 = NEXP * 16 * (HDIM / 128);
  const int g2 = NEXP * 16 * (DMODEL / 128);
  const int gw1 = NEXP * (DMODEL / 64) * (HDIM / 64);
  const int gw2 = NEXP * (HDIM / 64) * (DMODEL / 64);

  if (tier == 0) {
    k_wt<<<gw1, 256, 0, stream>>>(W1, DMODEL, HDIM, Whi, Wlo, 1);
    k_gemm<DMODEL, HDIM, true, 0, true><<<g1, 256, 0, stream>>>(
        xhi, xlo, Whi, Wlo, b1, counts, bases, pair_token, pair_w, hhi, hlo, nullptr);
    k_wt<<<gw2, 256, 0, stream>>>(W2, HDIM, DMODEL, Whi, Wlo, 1);
    k_gemm<HDIM, DMODEL, false, 0, false><<<g2, 256, 0, stream>>>(
        hhi, hlo, Whi, Wlo, b2, counts, bases, pair_token, pair_w, nullptr, nullptr, out);
  } else if (tier == 1) {
    k_wt<<<gw1, 256, 0, stream>>>(W1, DMODEL, HDIM, Whi, Wlo, 1);
    k_gemm<DMODEL, HDIM, true, 0, false><<<g1, 256, 0, stream>>>(
        xhi, xlo, Whi, Wlo, b1, counts, bases, pair_token, pair_w, hhi, hhi, nullptr);
    k_wt<<<gw2, 256, 0, stream>>>(W2, HDIM, DMODEL, Whi, Wlo, 1);
    k_gemm<HDIM, DMODEL, false, 1, false><<<g2, 256, 0, stream>>>(
        hhi, hhi, Whi, Wlo, b2, counts, bases, pair_token, pair_w, nullptr, nullptr, out);
  } else {
    k_wt<<<gw1, 256, 0, stream>>>(W1, DMODEL, HDIM, Whi, Whi, 0);
    k_gemm<DMODEL, HDIM, true, 2, false><<<g1, 256, 0, stream>>>(
        xhi, xlo, Whi, Whi, b1, counts, bases, pair_token, pair_w, hhi, hhi, nullptr);
    k_wt<<<gw2, 256, 0, stream>>>(W2, HDIM, DMODEL, Whi, Whi, 0);
    k_gemm<HDIM, DMODEL, false, 3, false><<<g2, 256, 0, stream>>>(
        hhi, hhi, Whi, Whi, b2, counts, bases, pair_token, pair_w, nullptr, nullptr, out);
  }
}